// Round 1
// baseline (469.902 us; speedup 1.0000x reference)
//
#include <hip/hip_runtime.h>
#include <hip/hip_bf16.h>

// PWC-Net correlation: out[b, dy*9+dx, y, x] =
//   (1/C) * sum_c first[b,c,y,x] * second[b,c, y+dy-4, x+dx-4]  (zero-padded)
// B=8, C=128, H=W=128, DISP=9, PAD=4.
//
// Block = 576 threads (9 waves) handles (b, y0..y0+1).
//   wave w = dy in [0,9); lane: yi = lane/32, xq = lane%32 -> x0 = 4*xq.
//   Thread owns 9 dx x 4 x positions = 36 fp32 accumulators.
// Channel-chunked LDS staging (Cc=8): per channel a thread does
//   36 FMA vs 4 ds_read_b128 -> VALU-dominant inner loop.

#define B  8
#define C  128
#define H  128
#define W  128
#define CC 8          // channels per LDS chunk
#define YB 2          // y rows per block
#define NTHR 576      // 9 waves

__global__ __launch_bounds__(NTHR, 2)
void ModuleCorrelation_41970420416706_kernel(const float* __restrict__ first,
                                             const float* __restrict__ second,
                                             float* __restrict__ out) {
    __shared__ float sFirst[CC][YB][W];            // 8 KiB
    __shared__ float sSec[CC][YB + 8][W + 8];      // 43.5 KiB (rows y0-4 .. y0+5, x -4..131)

    const int b  = blockIdx.x >> 6;          // /(H/YB)=64
    const int y0 = (blockIdx.x & 63) * YB;

    const int t    = threadIdx.x;
    const int dy   = t >> 6;                 // wave index = dy
    const int lane = t & 63;
    const int yi   = lane >> 5;
    const int x0   = (lane & 31) * 4;

    float acc[9][4];
#pragma unroll
    for (int dx = 0; dx < 9; ++dx)
#pragma unroll
        for (int j = 0; j < 4; ++j) acc[dx][j] = 0.f;

    for (int chunk = 0; chunk < C / CC; ++chunk) {
        const int cbase = chunk * CC;

        // ---- stage first rows: CC*YB*W = 2048 elems ----
        for (int idx = t; idx < CC * YB * W; idx += NTHR) {
            const int c   = idx >> 8;          // /(YB*W)
            const int rem = idx & 255;
            const int yy  = rem >> 7;
            const int xx  = rem & 127;
            sFirst[c][yy][xx] =
                first[(((b * C + cbase + c) * H) + y0 + yy) * W + xx];
        }
        // ---- stage second rows: CC*10*136 = 10880 elems (zero-padded) ----
        for (int idx = t; idx < CC * (YB + 8) * (W + 8); idx += NTHR) {
            const int c   = idx / ((YB + 8) * (W + 8));       // /1360
            const int rem = idx - c * ((YB + 8) * (W + 8));
            const int rr  = rem / (W + 8);
            const int xx  = rem - rr * (W + 8);
            const int ys  = y0 + rr - 4;
            const int xs  = xx - 4;
            float v = 0.f;
            if (ys >= 0 && ys < H && xs >= 0 && xs < W)
                v = second[(((b * C + cbase + c) * H) + ys) * W + xs];
            sSec[c][rr][xx] = v;
        }
        __syncthreads();

        // ---- compute: 36 FMA per channel per thread ----
#pragma unroll
        for (int c = 0; c < CC; ++c) {
            const float4 f = *(const float4*)&sFirst[c][yi][x0];
            const float* srow = &sSec[c][yi + dy][x0];
            const float4 sa = *(const float4*)(srow);
            const float4 sb = *(const float4*)(srow + 4);
            const float4 sc = *(const float4*)(srow + 8);
            const float s[12] = {sa.x, sa.y, sa.z, sa.w,
                                 sb.x, sb.y, sb.z, sb.w,
                                 sc.x, sc.y, sc.z, sc.w};
#pragma unroll
            for (int dx = 0; dx < 9; ++dx) {
                acc[dx][0] += f.x * s[dx + 0];
                acc[dx][1] += f.y * s[dx + 1];
                acc[dx][2] += f.z * s[dx + 2];
                acc[dx][3] += f.w * s[dx + 3];
            }
        }
        __syncthreads();
    }

    // ---- epilogue: scale by 1/C, vectorized stores ----
    const float scale = 1.0f / (float)C;
    const int yOut = y0 + yi;
#pragma unroll
    for (int dx = 0; dx < 9; ++dx) {
        const int tc = dy * 9 + dx;
        float4 o;
        o.x = acc[dx][0] * scale;
        o.y = acc[dx][1] * scale;
        o.z = acc[dx][2] * scale;
        o.w = acc[dx][3] * scale;
        *(float4*)&out[(((b * 81 + tc) * H) + yOut) * W + x0] = o;
    }
}

extern "C" void kernel_launch(void* const* d_in, const int* in_sizes, int n_in,
                              void* d_out, int out_size, void* d_ws, size_t ws_size,
                              hipStream_t stream) {
    const float* first  = (const float*)d_in[0];
    const float* second = (const float*)d_in[1];
    float* out = (float*)d_out;

    dim3 grid(B * (H / YB));   // 512 blocks
    dim3 block(NTHR);          // 576 threads = 9 waves
    ModuleCorrelation_41970420416706_kernel<<<grid, block, 0, stream>>>(first, second, out);
}

// Round 2
// 310.647 us; speedup vs baseline: 1.5127x; 1.5127x over previous
//
#include <hip/hip_runtime.h>
#include <hip/hip_bf16.h>

// PWC-Net correlation: out[b, dy*9+dx, y, x] =
//   (1/C) * sum_c first[b,c,y,x] * second[b,c, y+dy-4, x+dx-4]  (zero-padded)
// B=8, C=128, H=W=128, DISP=9, PAD=4.
//
// Round 2: software-pipelined, double-buffered LDS (CC=4), float4 staging.
//  - Block = 576 threads (9 waves) handles (b, y0..y0+1); wave = dy.
//  - Pads of sSec are zeroed ONCE; staging only writes the interior (aligned
//    float4) and skips out-of-range rows, so zero-padding is preserved.
//  - Pipeline: loads for chunk k+2 are in flight while chunk k computes;
//    one barrier per chunk (write buf^1 / read buf are disjoint).

#define B  8
#define C  128
#define H  128
#define W  128
#define CC 4
#define YB 2
#define NTHR 576
#define NCHUNK (C / CC)          // 32
#define SROWS (YB + 8)           // 10
#define SW    (W + 8)            // 136
#define NSEC4 (CC * SROWS * (W / 4))   // 1280 float4 interior per chunk
#define NFIR4 (CC * YB * (W / 4))      // 256 float4 per chunk

__global__ __launch_bounds__(NTHR, 2)
void ModuleCorrelation_41970420416706_kernel(const float* __restrict__ first,
                                             const float* __restrict__ second,
                                             float* __restrict__ out) {
    __shared__ __align__(16) float sFirst[2][CC][YB][W];     // 8 KiB
    __shared__ __align__(16) float sSec[2][CC][SROWS][SW];   // 43.5 KiB

    const int b  = blockIdx.x >> 6;          // /(H/YB)=64
    const int y0 = (blockIdx.x & 63) * YB;

    const int t    = threadIdx.x;
    const int dy   = t >> 6;                 // wave index = dy
    const int lane = t & 63;
    const int yi   = lane >> 5;
    const int x0   = (lane & 31) * 4;

    const float* firstB  = first  + (size_t)b * C * H * W;
    const float* secondB = second + (size_t)b * C * H * W;

    // ---- prefetch registers ----
    float4 rF;
    float4 rS[3];

    // first-staging coords (fixed per thread): t < 256 -> (c, yy, q)
    const bool hasF = (t < NFIR4);
    const int fc = t >> 6;                   // /(YB*W/4)
    const int fy = (t >> 5) & 1;
    const int fq = t & 31;

    auto issueLoads = [&](int chunk) {
        const int cbase = chunk * CC;
        if (hasF)
            rF = *(const float4*)&firstB[((cbase + fc) * H + y0 + fy) * W + fq * 4];
#pragma unroll
        for (int i = 0; i < 3; ++i) {
            const int idx = t + i * NTHR;
            if (idx < NSEC4) {
                const int c   = idx / (SROWS * (W / 4));        // /320
                const int rem = idx - c * (SROWS * (W / 4));
                const int rr  = rem >> 5;
                const int q   = rem & 31;
                const int ys  = y0 + rr - 4;
                if (ys >= 0 && ys < H)
                    rS[i] = *(const float4*)&secondB[((cbase + c) * H + ys) * W + q * 4];
            }
        }
    };

    auto writeLDS = [&](int buf, int chunk) {
        (void)chunk;
        if (hasF)
            *(float4*)&sFirst[buf][fc][fy][fq * 4] = rF;
#pragma unroll
        for (int i = 0; i < 3; ++i) {
            const int idx = t + i * NTHR;
            if (idx < NSEC4) {
                const int c   = idx / (SROWS * (W / 4));
                const int rem = idx - c * (SROWS * (W / 4));
                const int rr  = rem >> 5;
                const int q   = rem & 31;
                const int ys  = y0 + rr - 4;
                if (ys >= 0 && ys < H)
                    *(float4*)&sSec[buf][c][rr][4 + q * 4] = rS[i];
            }
        }
    };

    float acc[9][4];
#pragma unroll
    for (int dx = 0; dx < 9; ++dx)
#pragma unroll
        for (int j = 0; j < 4; ++j) acc[dx][j] = 0.f;

    // ---- prologue ----
    issueLoads(0);                      // chunk-0 loads in flight during zeroing
    {
        const float4 z = make_float4(0.f, 0.f, 0.f, 0.f);
        float4* p = (float4*)sSec;
        for (int i = t; i < 2 * CC * SROWS * SW / 4; i += NTHR) p[i] = z;  // 2720
    }
    __syncthreads();                    // zero-fill visible before interior writes
    writeLDS(0, 0);
    issueLoads(1);
    __syncthreads();                    // buf0 ready

    // ---- main pipeline: one barrier per chunk ----
    for (int k = 0; k < NCHUNK; ++k) {
        const int buf = k & 1;

#pragma unroll
        for (int c = 0; c < CC; ++c) {
            const float4 f = *(const float4*)&sFirst[buf][c][yi][x0];
            const float* srow = &sSec[buf][c][yi + dy][x0];
            const float4 sa = *(const float4*)(srow);
            const float4 sb = *(const float4*)(srow + 4);
            const float4 sc = *(const float4*)(srow + 8);
            const float s[12] = {sa.x, sa.y, sa.z, sa.w,
                                 sb.x, sb.y, sb.z, sb.w,
                                 sc.x, sc.y, sc.z, sc.w};
#pragma unroll
            for (int dx = 0; dx < 9; ++dx) {
                acc[dx][0] += f.x * s[dx + 0];
                acc[dx][1] += f.y * s[dx + 1];
                acc[dx][2] += f.z * s[dx + 2];
                acc[dx][3] += f.w * s[dx + 3];
            }
        }

        if (k + 1 < NCHUNK) {
            writeLDS(buf ^ 1, k + 1);   // vmcnt wait here — loads landed during compute
            if (k + 2 < NCHUNK) issueLoads(k + 2);
        }
        __syncthreads();
    }

    // ---- epilogue: scale by 1/C, vectorized stores ----
    const float scale = 1.0f / (float)C;
    const int yOut = y0 + yi;
#pragma unroll
    for (int dx = 0; dx < 9; ++dx) {
        const int tc = dy * 9 + dx;
        float4 o;
        o.x = acc[dx][0] * scale;
        o.y = acc[dx][1] * scale;
        o.z = acc[dx][2] * scale;
        o.w = acc[dx][3] * scale;
        *(float4*)&out[(((b * 81 + tc) * H) + yOut) * W + x0] = o;
    }
}

extern "C" void kernel_launch(void* const* d_in, const int* in_sizes, int n_in,
                              void* d_out, int out_size, void* d_ws, size_t ws_size,
                              hipStream_t stream) {
    const float* first  = (const float*)d_in[0];
    const float* second = (const float*)d_in[1];
    float* out = (float*)d_out;

    dim3 grid(B * (H / YB));   // 512 blocks
    dim3 block(NTHR);          // 576 threads = 9 waves
    ModuleCorrelation_41970420416706_kernel<<<grid, block, 0, stream>>>(first, second, out);
}